// Round 6
// baseline (104.548 us; speedup 1.0000x reference)
//
#include <hip/hip_runtime.h>
#include <hip/hip_bf16.h>

// out[t,z] = sum_i f[t,i] * ( sum_j a[t,j] * C[i,j,z] )
// R6: kill the LDS B-path. Pre-transpose C -> CT[i][z][j] bf16 (in ws), then the
// main K-loop loads B-fragments straight from global (j-contiguous, coalesced
// 64 B/row), NO __syncthreads in the K-loop, register double-buffer prefetch.
// Main: block 256 thr = 4 waves (one 16-z slice each), tile M=128 (8 m-subtiles
// per wave, a_pk=128 VGPR), N=64, 16 i-slabs. Grid 512 = 32 mt x 2 zp x 8 kp;
// kp=bid&7 -> XCD-affine CT chunk (512 KB) lives in that XCD's L2.
// ws: [0,16MB) fp32 partials [kp][4096][128]; [16MB,20MB) CT bf16.

typedef __attribute__((ext_vector_type(8))) short bf16x8;
typedef __attribute__((ext_vector_type(4))) float f32x4;

__device__ __forceinline__ unsigned pkbf16(float x, float y) {
    __hip_bfloat162 h = __float22bfloat162_rn(make_float2(x, y));
    unsigned u; __builtin_memcpy(&u, &h, sizeof(u));
    return u;
}

// ---------- transpose C[i][j][z] fp32 -> CT[i][z][j] bf16 ----------
__global__ __launch_bounds__(256) void cooc_transpose(
    const float* __restrict__ Cc, ushort* __restrict__ CT)
{
    __shared__ float tile[32][132];        // 16.9 KB, stride 132 (16B-aligned rows)
    const int i  = blockIdx.x >> 2;
    const int j0 = (blockIdx.x & 3) * 32;  // j-quarter
    const int t  = threadIdx.x;

    {   // read 32 j-rows x 128 z, coalesced along z
        const int jj = t >> 3;
        const int zb = (t & 7) * 16;
        const float* src = Cc + (size_t)i * 16384 + (size_t)(j0 + jj) * 128 + zb;
        #pragma unroll
        for (int k = 0; k < 4; ++k)
            *(float4*)&tile[jj][zb + k * 4] = *(const float4*)(src + k * 4);
    }
    __syncthreads();
    {   // write 128 z-rows x 32 j bf16, coalesced along j
        const int z = t >> 1;
        const int h = t & 1;
        unsigned o[8];
        #pragma unroll
        for (int p = 0; p < 8; ++p)        // LDS column reads: bank=(4j+z)&31, 2-way max
            o[p] = pkbf16(tile[h * 16 + 2 * p][z], tile[h * 16 + 2 * p + 1][z]);
        ushort* dst = CT + (size_t)i * 16384 + (size_t)z * 128 + j0 + h * 16;
        *(uint4*)dst       = make_uint4(o[0], o[1], o[2], o[3]);
        *(uint4*)(dst + 8) = make_uint4(o[4], o[5], o[6], o[7]);
    }
}

// ---------- main: direct-global B, barrier-free K-loop ----------
template<int USE_WS>
__global__ __launch_bounds__(256, 2) void cooc_main(
    const float* __restrict__ fa, const ushort* __restrict__ CT,
    float* __restrict__ dst)   // USE_WS: partials [kp][4096*128]; else out (atomic)
{
    __shared__ float f_lds[16][128];       // 8 KB: f[i_local][row]

    const int bid = blockIdx.x;
    const int kp = bid & 7, zp = (bid >> 3) & 1, mtile = bid >> 4;
    const int t0 = mtile * 128, i0 = kp * 16, z0 = zp * 64;
    const int tid = threadIdx.x, lane = tid & 63, wv = tid >> 6;
    const int lm = lane & 15, lk = lane >> 4;

    // stage f -> LDS (transposed [i][row]); bank = row&31 -> 2-way, free
    {
        const int row = tid & 127;
        const int sh = (tid >> 7) * 8;
        const float* fp = fa + (size_t)(t0 + row) * 256 + i0 + sh;
        float4 v0 = *(const float4*)fp;
        float4 v1 = *(const float4*)(fp + 4);
        f_lds[sh + 0][row] = v0.x; f_lds[sh + 1][row] = v0.y;
        f_lds[sh + 2][row] = v0.z; f_lds[sh + 3][row] = v0.w;
        f_lds[sh + 4][row] = v1.x; f_lds[sh + 5][row] = v1.y;
        f_lds[sh + 6][row] = v1.z; f_lds[sh + 7][row] = v1.w;
    }

    // pack A ONCE: 8 m-subtiles x 4 ks = 128 VGPR. A[m=lm][k=lk*8+e]
    union { unsigned u[4]; bf16x8 v; } a_pk[8][4];
    #pragma unroll
    for (int m = 0; m < 8; ++m) {
        const float* ab = fa + (size_t)(t0 + m * 16 + lm) * 256 + 128;
        #pragma unroll
        for (int ks = 0; ks < 4; ++ks) {
            float4 q0 = *(const float4*)(ab + ks * 32 + lk * 8);
            float4 q1 = *(const float4*)(ab + ks * 32 + lk * 8 + 4);
            a_pk[m][ks].u[0] = pkbf16(q0.x, q0.y);
            a_pk[m][ks].u[1] = pkbf16(q0.z, q0.w);
            a_pk[m][ks].u[2] = pkbf16(q1.x, q1.y);
            a_pk[m][ks].u[3] = pkbf16(q1.z, q1.w);
        }
    }
    __syncthreads();   // f_lds ready; the ONLY barrier

    // B-frag source: CT[i0+s][z0 + wv*16 + lm][ks*32 + lk*8 ..+7]
    // lanes: 16 z-rows x 4 lk-chunks = 16 coalesced 64 B segments per load group
    const ushort* bsrc = CT + (size_t)i0 * 16384
                            + (size_t)(z0 + wv * 16 + lm) * 128 + lk * 8;

    bf16x8 B[2][4];
    #pragma unroll
    for (int ks = 0; ks < 4; ++ks)
        B[0][ks] = *(const bf16x8*)(bsrc + ks * 32);

    float acc[8][4];
    #pragma unroll
    for (int m = 0; m < 8; ++m)
        #pragma unroll
        for (int r = 0; r < 4; ++r) acc[m][r] = 0.f;

    #pragma unroll 2
    for (int s = 0; s < 16; ++s) {
        const int cur = s & 1;
        if (s < 15) {                       // register prefetch for s+1 (stays in flight)
            const ushort* p = bsrc + (size_t)(s + 1) * 16384;
            #pragma unroll
            for (int ks = 0; ks < 4; ++ks)
                B[cur ^ 1][ks] = *(const bf16x8*)(p + ks * 32);
        }
        #pragma unroll
        for (int m = 0; m < 8; ++m) {
            float4 f4 = *(const float4*)&f_lds[s][m * 16 + lk * 4];  // broadcast b128
            f32x4 g = {0.f, 0.f, 0.f, 0.f};
            #pragma unroll
            for (int ks = 0; ks < 4; ++ks)
                g = __builtin_amdgcn_mfma_f32_16x16x32_bf16(a_pk[m][ks].v, B[cur][ks], g, 0, 0, 0);
            acc[m][0] += f4.x * g[0];
            acc[m][1] += f4.y * g[1];
            acc[m][2] += f4.z * g[2];
            acc[m][3] += f4.w * g[3];
        }
    }

    // epilogue: C/D col=lm, row=lk*4+r
    const int col = z0 + wv * 16 + lm;
    #pragma unroll
    for (int m = 0; m < 8; ++m)
        #pragma unroll
        for (int r = 0; r < 4; ++r) {
            const int row = t0 + m * 16 + lk * 4 + r;
            if (USE_WS)
                dst[(size_t)kp * 524288 + (size_t)row * 128 + col] = acc[m][r];
            else
                atomicAdd(&dst[(size_t)row * 128 + col], acc[m][r]);
        }
}

__global__ __launch_bounds__(256) void cooc_reduce(const float* __restrict__ ws,
                                                   float* __restrict__ out) {
    const size_t idx = ((size_t)blockIdx.x * 256 + threadIdx.x) * 4;
    float4 a = *(const float4*)(ws + idx);
    #pragma unroll
    for (int k = 1; k < 8; ++k) {
        float4 b = *(const float4*)(ws + (size_t)k * 524288 + idx);
        a.x += b.x; a.y += b.y; a.z += b.z; a.w += b.w;
    }
    *(float4*)(out + idx) = a;
}

// ---------- proven R5 fallback (only if ws can't hold CT) ----------
__global__ __launch_bounds__(256, 2) void cooc_fb(
    const float* __restrict__ fa, const float* __restrict__ Cc,
    float* __restrict__ dst)
{
    __shared__ __align__(16) ushort bT[2][64 * 136];
    __shared__ float f_lds[16][128];
    const int bid = blockIdx.x;
    const int kp = bid & 7, zp = (bid >> 3) & 1, mtile = bid >> 4;
    const int t0 = mtile * 128, i0 = kp * 16, z0 = zp * 64;
    const int tid = threadIdx.x, lane = tid & 63, wv = tid >> 6;
    const int mg = wv >> 1, zg = wv & 1, lm = lane & 15, lk = lane >> 4;
    {
        const int row = tid & 127;
        const int sh = (tid >> 7) * 8;
        const float* fp = fa + (size_t)(t0 + row) * 256 + i0 + sh;
        float4 v0 = *(const float4*)fp;
        float4 v1 = *(const float4*)(fp + 4);
        f_lds[sh + 0][row] = v0.x; f_lds[sh + 1][row] = v0.y;
        f_lds[sh + 2][row] = v0.z; f_lds[sh + 3][row] = v0.w;
        f_lds[sh + 4][row] = v1.x; f_lds[sh + 5][row] = v1.y;
        f_lds[sh + 6][row] = v1.z; f_lds[sh + 7][row] = v1.w;
    }
    union { unsigned u[4]; bf16x8 v; } a_pk[4][4];
    #pragma unroll
    for (int m = 0; m < 4; ++m) {
        const float* ab = fa + (size_t)(t0 + mg * 64 + m * 16 + lm) * 256 + 128;
        #pragma unroll
        for (int ks = 0; ks < 4; ++ks) {
            float4 q0 = *(const float4*)(ab + ks * 32 + lk * 8);
            float4 q1 = *(const float4*)(ab + ks * 32 + lk * 8 + 4);
            a_pk[m][ks].u[0] = pkbf16(q0.x, q0.y);
            a_pk[m][ks].u[1] = pkbf16(q0.z, q0.w);
            a_pk[m][ks].u[2] = pkbf16(q1.x, q1.y);
            a_pk[m][ks].u[3] = pkbf16(q1.z, q1.w);
        }
    }
    const int zq = tid & 15, jq0 = tid >> 4;
    const float* csrc0 = Cc + (size_t)i0 * 16384 + (size_t)(jq0 * 4) * 128 + z0 + zq * 4;
    const float* csrc1 = csrc0 + 16 * 4 * 128;
    union { float4 v4[4]; float f[16]; } La[2];
    auto loads = [&](int s) {
        const float* p0 = csrc0 + (size_t)s * 16384;
        const float* p1 = csrc1 + (size_t)s * 16384;
        #pragma unroll
        for (int r = 0; r < 4; ++r) {
            La[0].v4[r] = *(const float4*)(p0 + r * 128);
            La[1].v4[r] = *(const float4*)(p1 + r * 128);
        }
    };
    auto writes = [&](int b) {
        #pragma unroll
        for (int part = 0; part < 2; ++part) {
            const int jq = jq0 + part * 16;
            const int pos = ((jq >> 1) + zq) & 15;
            #pragma unroll
            for (int rr = 0; rr < 4; ++rr) {
                const int zl = zq * 4 + rr;
                const unsigned lo = pkbf16(La[part].f[0 * 4 + rr], La[part].f[1 * 4 + rr]);
                const unsigned hi = pkbf16(La[part].f[2 * 4 + rr], La[part].f[3 * 4 + rr]);
                *(uint2*)&bT[b][zl * 136 + pos * 8 + (jq & 1) * 4] = make_uint2(lo, hi);
            }
        }
    };
    loads(0); writes(0);
    __syncthreads();
    float acc[4][2][4];
    #pragma unroll
    for (int m = 0; m < 4; ++m)
        #pragma unroll
        for (int n = 0; n < 2; ++n)
            #pragma unroll
            for (int r = 0; r < 4; ++r) acc[m][n][r] = 0.f;
    #pragma unroll 2
    for (int s = 0; s < 16; ++s) {
        const int p = s & 1;
        if (s < 15) loads(s + 1);
        float4 f4[4];
        #pragma unroll
        for (int m = 0; m < 4; ++m)
            f4[m] = *(const float4*)&f_lds[s][mg * 64 + m * 16 + lk * 4];
        bf16x8 Bf[4][2];
        #pragma unroll
        for (int ks = 0; ks < 4; ++ks)
            #pragma unroll
            for (int n = 0; n < 2; ++n) {
                const int zz = zg * 32 + n * 16 + lm;
                const int pos = ((ks * 4 + lk) + (zz >> 2)) & 15;
                Bf[ks][n] = *(const bf16x8*)&bT[p][zz * 136 + pos * 8];
            }
        #pragma unroll
        for (int m = 0; m < 4; ++m)
            #pragma unroll
            for (int n = 0; n < 2; ++n) {
                f32x4 g = {0.f, 0.f, 0.f, 0.f};
                #pragma unroll
                for (int ks = 0; ks < 4; ++ks)
                    g = __builtin_amdgcn_mfma_f32_16x16x32_bf16(a_pk[m][ks].v, Bf[ks][n], g, 0, 0, 0);
                acc[m][n][0] += f4[m].x * g[0];
                acc[m][n][1] += f4[m].y * g[1];
                acc[m][n][2] += f4[m].z * g[2];
                acc[m][n][3] += f4[m].w * g[3];
            }
        if (s < 15) writes(p ^ 1);
        __syncthreads();
    }
    #pragma unroll
    for (int m = 0; m < 4; ++m)
        #pragma unroll
        for (int n = 0; n < 2; ++n)
            #pragma unroll
            for (int r = 0; r < 4; ++r) {
                const int row = t0 + mg * 64 + m * 16 + lk * 4 + r;
                const int col = z0 + zg * 32 + n * 16 + lm;
                atomicAdd(&dst[(size_t)row * 128 + col], acc[m][n][r]);
            }
}

extern "C" void kernel_launch(void* const* d_in, const int* in_sizes, int n_in,
                              void* d_out, int out_size, void* d_ws, size_t ws_size,
                              hipStream_t stream) {
    const float* fa = (const float*)d_in[0];   // (4096,256): [:,0:128]=f, [:,128:256]=a
    const float* Cc = (const float*)d_in[1];   // (128,128,128)
    float* out = (float*)d_out;                // (4096,128)

    const size_t PART = (size_t)8 * 524288;            // fp32 partials: 16 MiB
    const size_t CTOF = PART * sizeof(float);
    const size_t NEED_FULL = CTOF + (size_t)128 * 128 * 128 * 2;   // +4 MiB CT
    const size_t NEED_CT   = (size_t)128 * 128 * 128 * 2;

    if (ws_size >= NEED_FULL) {
        ushort* CT = (ushort*)((char*)d_ws + CTOF);
        cooc_transpose<<<512, 256, 0, stream>>>(Cc, CT);
        cooc_main<1><<<512, 256, 0, stream>>>(fa, CT, (float*)d_ws);
        cooc_reduce<<<512, 256, 0, stream>>>((const float*)d_ws, out);
    } else if (ws_size >= NEED_CT) {
        ushort* CT = (ushort*)d_ws;
        cooc_transpose<<<512, 256, 0, stream>>>(Cc, CT);
        (void)hipMemsetAsync(out, 0, (size_t)out_size * sizeof(float), stream);
        cooc_main<0><<<512, 256, 0, stream>>>(fa, CT, out);
    } else {
        (void)hipMemsetAsync(out, 0, (size_t)out_size * sizeof(float), stream);
        cooc_fb<<<512, 256, 0, stream>>>(fa, Cc, out);
    }
}

// Round 8
// 102.647 us; speedup vs baseline: 1.0185x; 1.0185x over previous
//
#include <hip/hip_runtime.h>
#include <hip/hip_bf16.h>

// out[t,z] = sum_i f[t,i] * ( sum_j a[t,j] * C[i,j,z] )
// R8 = R6's proven-passing skeleton (transpose -> main -> reduce, identical
// staging/addressing/epilogue) + ONE change: ILP restructure of the MFMA loop.
// Per slab, m processed in 2 halves of 4: hoist 4 f4 ds_reads, then
// ks-outer/m-inner MFMA -> 4 independent g-chains (dep distance 4), then fold.
// Wave tile 128x16 (a_pk[8][4]=128 regs), block 4 waves (one 16-z slice each).
// Grid 512 = 32 mt x 2 zp x 8 kp; kp=bid&7 -> XCD-affine CT chunk in L2.
// ws: [0,16MB) fp32 partials [kp][4096][128]; [16MB,20MB) CT bf16 [i][z][j].

typedef __attribute__((ext_vector_type(8))) short bf16x8;
typedef __attribute__((ext_vector_type(4))) float f32x4;

__device__ __forceinline__ unsigned pkbf16(float x, float y) {
    __hip_bfloat162 h = __float22bfloat162_rn(make_float2(x, y));
    unsigned u; __builtin_memcpy(&u, &h, sizeof(u));
    return u;
}

// ---------- transpose C[i][j][z] fp32 -> CT[i][z][j] bf16 (verbatim R6) ----------
__global__ __launch_bounds__(256) void cooc_transpose(
    const float* __restrict__ Cc, ushort* __restrict__ CT)
{
    __shared__ float tile[32][132];
    const int i  = blockIdx.x >> 2;
    const int j0 = (blockIdx.x & 3) * 32;
    const int t  = threadIdx.x;
    {
        const int jj = t >> 3;
        const int zb = (t & 7) * 16;
        const float* src = Cc + (size_t)i * 16384 + (size_t)(j0 + jj) * 128 + zb;
        #pragma unroll
        for (int k = 0; k < 4; ++k)
            *(float4*)&tile[jj][zb + k * 4] = *(const float4*)(src + k * 4);
    }
    __syncthreads();
    {
        const int z = t >> 1;
        const int h = t & 1;
        unsigned o[8];
        #pragma unroll
        for (int p = 0; p < 8; ++p)
            o[p] = pkbf16(tile[h * 16 + 2 * p][z], tile[h * 16 + 2 * p + 1][z]);
        ushort* dst = CT + (size_t)i * 16384 + (size_t)z * 128 + j0 + h * 16;
        *(uint4*)dst       = make_uint4(o[0], o[1], o[2], o[3]);
        *(uint4*)(dst + 8) = make_uint4(o[4], o[5], o[6], o[7]);
    }
}

// ---------- main (R6 skeleton, ILP-restructured inner loop) ----------
template<int USE_WS>
__global__ __launch_bounds__(256, 2) void cooc_main(
    const float* __restrict__ fa, const ushort* __restrict__ CT,
    float* __restrict__ dst)
{
    __shared__ float f_lds[16][128];       // 8 KB: f[i_local][row]

    const int bid = blockIdx.x;
    const int kp = bid & 7, zp = (bid >> 3) & 1, mtile = bid >> 4;
    const int t0 = mtile * 128, i0 = kp * 16, z0 = zp * 64;
    const int tid = threadIdx.x, lane = tid & 63, wv = tid >> 6;
    const int lm = lane & 15, lk = lane >> 4;

    // stage f -> LDS (transposed [i][row])  (verbatim R6)
    {
        const int row = tid & 127;
        const int sh = (tid >> 7) * 8;
        const float* fp = fa + (size_t)(t0 + row) * 256 + i0 + sh;
        float4 v0 = *(const float4*)fp;
        float4 v1 = *(const float4*)(fp + 4);
        f_lds[sh + 0][row] = v0.x; f_lds[sh + 1][row] = v0.y;
        f_lds[sh + 2][row] = v0.z; f_lds[sh + 3][row] = v0.w;
        f_lds[sh + 4][row] = v1.x; f_lds[sh + 5][row] = v1.y;
        f_lds[sh + 6][row] = v1.z; f_lds[sh + 7][row] = v1.w;
    }

    // pack A ONCE: 8 m-subtiles x 4 ks = 128 regs. A[m=lm][k=lk*8+e] (verbatim R6)
    union { unsigned u[4]; bf16x8 v; } a_pk[8][4];
    #pragma unroll
    for (int m = 0; m < 8; ++m) {
        const float* ab = fa + (size_t)(t0 + m * 16 + lm) * 256 + 128;
        #pragma unroll
        for (int ks = 0; ks < 4; ++ks) {
            float4 q0 = *(const float4*)(ab + ks * 32 + lk * 8);
            float4 q1 = *(const float4*)(ab + ks * 32 + lk * 8 + 4);
            a_pk[m][ks].u[0] = pkbf16(q0.x, q0.y);
            a_pk[m][ks].u[1] = pkbf16(q0.z, q0.w);
            a_pk[m][ks].u[2] = pkbf16(q1.x, q1.y);
            a_pk[m][ks].u[3] = pkbf16(q1.z, q1.w);
        }
    }
    __syncthreads();   // f_lds ready; only barrier

    // B source (verbatim R6): CT[i0+s][z0 + wv*16 + lm][ks*32 + lk*8 ..+7]
    const ushort* bsrc = CT + (size_t)i0 * 16384
                            + (size_t)(z0 + wv * 16 + lm) * 128 + lk * 8;

    bf16x8 B[2][4];
    #pragma unroll
    for (int ks = 0; ks < 4; ++ks)
        B[0][ks] = *(const bf16x8*)(bsrc + ks * 32);

    float acc[8][4];
    #pragma unroll
    for (int m = 0; m < 8; ++m)
        #pragma unroll
        for (int r = 0; r < 4; ++r) acc[m][r] = 0.f;

    #pragma unroll 2
    for (int s = 0; s < 16; ++s) {
        const int cur = s & 1;
        if (s < 15) {                       // prefetch next slab (verbatim R6)
            const ushort* p = bsrc + (size_t)(s + 1) * 16384;
            #pragma unroll
            for (int ks = 0; ks < 4; ++ks)
                B[cur ^ 1][ks] = *(const bf16x8*)(p + ks * 32);
        }
        // m in 2 halves of 4: hoisted f4 reads + 4 independent MFMA chains
        #pragma unroll
        for (int h = 0; h < 2; ++h) {
            float4 f4[4];
            #pragma unroll
            for (int mm = 0; mm < 4; ++mm)
                f4[mm] = *(const float4*)&f_lds[s][(h * 4 + mm) * 16 + lk * 4];

            f32x4 g[4];
            #pragma unroll
            for (int mm = 0; mm < 4; ++mm) g[mm] = (f32x4){0.f, 0.f, 0.f, 0.f};

            #pragma unroll
            for (int ks = 0; ks < 4; ++ks)      // ks-outer: dep distance 4
                #pragma unroll
                for (int mm = 0; mm < 4; ++mm)
                    g[mm] = __builtin_amdgcn_mfma_f32_16x16x32_bf16(
                        a_pk[h * 4 + mm][ks].v, B[cur][ks], g[mm], 0, 0, 0);

            #pragma unroll
            for (int mm = 0; mm < 4; ++mm) {
                acc[h * 4 + mm][0] += f4[mm].x * g[mm][0];
                acc[h * 4 + mm][1] += f4[mm].y * g[mm][1];
                acc[h * 4 + mm][2] += f4[mm].z * g[mm][2];
                acc[h * 4 + mm][3] += f4[mm].w * g[mm][3];
            }
        }
    }

    // epilogue (verbatim R6): C/D col=lm, row=lk*4+r
    const int col = z0 + wv * 16 + lm;
    #pragma unroll
    for (int m = 0; m < 8; ++m)
        #pragma unroll
        for (int r = 0; r < 4; ++r) {
            const int row = t0 + m * 16 + lk * 4 + r;
            if (USE_WS)
                dst[(size_t)kp * 524288 + (size_t)row * 128 + col] = acc[m][r];
            else
                atomicAdd(&dst[(size_t)row * 128 + col], acc[m][r]);
        }
}

__global__ __launch_bounds__(256) void cooc_reduce(const float* __restrict__ ws,
                                                   float* __restrict__ out) {
    const size_t idx = ((size_t)blockIdx.x * 256 + threadIdx.x) * 4;
    float4 a = *(const float4*)(ws + idx);
    #pragma unroll
    for (int k = 1; k < 8; ++k) {
        float4 b = *(const float4*)(ws + (size_t)k * 524288 + idx);
        a.x += b.x; a.y += b.y; a.z += b.z; a.w += b.w;
    }
    *(float4*)(out + idx) = a;
}

extern "C" void kernel_launch(void* const* d_in, const int* in_sizes, int n_in,
                              void* d_out, int out_size, void* d_ws, size_t ws_size,
                              hipStream_t stream) {
    const float* fa = (const float*)d_in[0];   // (4096,256): [:,0:128]=f, [:,128:256]=a
    const float* Cc = (const float*)d_in[1];   // (128,128,128)
    float* out = (float*)d_out;                // (4096,128)

    const size_t PART = (size_t)8 * 524288;            // fp32 partials: 16 MiB
    const size_t CTOF = PART * sizeof(float);
    const size_t NEED_FULL = CTOF + (size_t)128 * 128 * 128 * 2;
    const size_t NEED_CT   = (size_t)128 * 128 * 128 * 2;

    if (ws_size >= NEED_FULL) {
        ushort* CT = (ushort*)((char*)d_ws + CTOF);
        cooc_transpose<<<512, 256, 0, stream>>>(Cc, CT);
        cooc_main<1><<<512, 256, 0, stream>>>(fa, CT, (float*)d_ws);
        cooc_reduce<<<512, 256, 0, stream>>>((const float*)d_ws, out);
    } else if (ws_size >= NEED_CT) {
        ushort* CT = (ushort*)d_ws;
        cooc_transpose<<<512, 256, 0, stream>>>(Cc, CT);
        (void)hipMemsetAsync(out, 0, (size_t)out_size * sizeof(float), stream);
        cooc_main<0><<<512, 256, 0, stream>>>(fa, CT, out);
    } else {
        (void)hipMemsetAsync(out, 0, (size_t)out_size * sizeof(float), stream);
        cooc_main<0><<<512, 256, 0, stream>>>(fa, (const ushort*)d_ws, out);
    }
}

// Round 9
// 89.035 us; speedup vs baseline: 1.1742x; 1.1529x over previous
//
#include <hip/hip_runtime.h>
#include <hip/hip_bf16.h>

// out[t,z] = sum_i f[t,i] * ( sum_j a[t,j] * C[i,j,z] )
// R9 = R8 skeleton + fragment-major operand layouts so every hot wave-load is
// ONE contiguous 1 KB segment (base + lane*16) instead of 16 scattered 64 B
// segments (R6/R8's 43 us plateau = TA/L1 segment serialization).
//  - CTf[i][g=z>>4][c=ks*4+lk][lm][8j]  bf16 (4 MB in ws)
//  - APK[grp=t>>4][ks][lk][lm][8k]      bf16 (1 MB in ws), A needs no VALU pack
// Main: wave tile 128x16, block 4 waves, grid 512 = 32mt x 2zp x 8kp (kp->XCD).
// ws: [0,16MB) fp32 partials; [16,20MB) CTf; [20,21MB) APK.

typedef __attribute__((ext_vector_type(8))) short bf16x8;
typedef __attribute__((ext_vector_type(4))) float f32x4;

__device__ __forceinline__ unsigned pkbf16(float x, float y) {
    __hip_bfloat162 h = __float22bfloat162_rn(make_float2(x, y));
    unsigned u; __builtin_memcpy(&u, &h, sizeof(u));
    return u;
}

// ---------- C[i][j][z] fp32 -> CTf[i][z>>4][j>>3][z&15][j&7] bf16 ----------
__global__ __launch_bounds__(256) void cooc_transpose(
    const float* __restrict__ Cc, ushort* __restrict__ CT)
{
    __shared__ float tile[32][132];
    const int i  = blockIdx.x >> 2;
    const int j0 = (blockIdx.x & 3) * 32;
    const int t  = threadIdx.x;
    {
        const int jj = t >> 3;
        const int zb = (t & 7) * 16;
        const float* src = Cc + (size_t)i * 16384 + (size_t)(j0 + jj) * 128 + zb;
        #pragma unroll
        for (int k = 0; k < 4; ++k)
            *(float4*)&tile[jj][zb + k * 4] = *(const float4*)(src + k * 4);
    }
    __syncthreads();
    {
        const int z = t >> 1;
        const int h = t & 1;
        unsigned o[8];
        #pragma unroll
        for (int p = 0; p < 8; ++p)
            o[p] = pkbf16(tile[h * 16 + 2 * p][z], tile[h * 16 + 2 * p + 1][z]);
        // dst chunks c0, c0+1 (16 j) at fragment-major offsets
        const int c0 = (j0 >> 3) + h * 2;
        ushort* dst = CT + (size_t)i * 16384 + (size_t)(z >> 4) * 2048
                         + (size_t)c0 * 128 + (z & 15) * 8;
        *(uint4*)dst         = make_uint4(o[0], o[1], o[2], o[3]);
        *(uint4*)(dst + 128) = make_uint4(o[4], o[5], o[6], o[7]);
    }
}

// ---------- a (fa[:,128:256]) -> APK[grp][ks][lk][lm][8] bf16 ----------
__global__ __launch_bounds__(256) void cooc_apack(
    const float* __restrict__ fa, ushort* __restrict__ APK)
{
    const int g = blockIdx.x;          // 16-row group, 0..255
    const int t = threadIdx.x;
    const int ks = t >> 6, lk = (t >> 4) & 3, lm = t & 15;
    const float* src = fa + (size_t)(g * 16 + lm) * 256 + 128 + ks * 32 + lk * 8;
    float4 q0 = *(const float4*)src;
    float4 q1 = *(const float4*)(src + 4);
    unsigned o0 = pkbf16(q0.x, q0.y), o1 = pkbf16(q0.z, q0.w);
    unsigned o2 = pkbf16(q1.x, q1.y), o3 = pkbf16(q1.z, q1.w);
    *(uint4*)(APK + (size_t)g * 2048 + t * 8) = make_uint4(o0, o1, o2, o3);
}

// ---------- main ----------
template<int USE_WS>
__global__ __launch_bounds__(256, 2) void cooc_main(
    const float* __restrict__ fa, const ushort* __restrict__ CT,
    const ushort* __restrict__ APK, float* __restrict__ dst)
{
    __shared__ float f_lds[16][128];       // 8 KB: f[i_local][row]

    const int bid = blockIdx.x;
    const int kp = bid & 7, zp = (bid >> 3) & 1, mtile = bid >> 4;
    const int t0 = mtile * 128, i0 = kp * 16, z0 = zp * 64;
    const int tid = threadIdx.x, lane = tid & 63, wv = tid >> 6;
    const int lm = lane & 15, lk = lane >> 4;

    // stage f -> LDS (transposed [i][row])
    {
        const int row = tid & 127;
        const int sh = (tid >> 7) * 8;
        const float* fp = fa + (size_t)(t0 + row) * 256 + i0 + sh;
        float4 v0 = *(const float4*)fp;
        float4 v1 = *(const float4*)(fp + 4);
        f_lds[sh + 0][row] = v0.x; f_lds[sh + 1][row] = v0.y;
        f_lds[sh + 2][row] = v0.z; f_lds[sh + 3][row] = v0.w;
        f_lds[sh + 4][row] = v1.x; f_lds[sh + 5][row] = v1.y;
        f_lds[sh + 6][row] = v1.z; f_lds[sh + 7][row] = v1.w;
    }

    // A fragments: 32 contiguous 1 KB wave-loads from APK (no pack VALU)
    bf16x8 a_pk[8][4];                     // 128 regs
    {
        const ushort* ap = APK + (size_t)(t0 >> 4) * 2048 + lane * 8;
        #pragma unroll
        for (int m = 0; m < 8; ++m)
            #pragma unroll
            for (int ks = 0; ks < 4; ++ks)
                a_pk[m][ks] = *(const bf16x8*)(ap + (size_t)m * 2048 + ks * 512);
    }
    __syncthreads();   // f_lds ready; only barrier

    // B source: contiguous — CTf + i*16384 + g*2048 + lane*8, +ks*512, +s*16384
    const ushort* bsrc = CT + (size_t)i0 * 16384
                            + (size_t)(zp * 4 + wv) * 2048 + lane * 8;

    bf16x8 B[2][4];
    #pragma unroll
    for (int ks = 0; ks < 4; ++ks)
        B[0][ks] = *(const bf16x8*)(bsrc + ks * 512);

    float acc[8][4];
    #pragma unroll
    for (int m = 0; m < 8; ++m)
        #pragma unroll
        for (int r = 0; r < 4; ++r) acc[m][r] = 0.f;

    #pragma unroll 2
    for (int s = 0; s < 16; ++s) {
        const int cur = s & 1;
        if (s < 15) {                       // prefetch next slab (4 x 1 KB contiguous)
            const ushort* p = bsrc + (size_t)(s + 1) * 16384;
            #pragma unroll
            for (int ks = 0; ks < 4; ++ks)
                B[cur ^ 1][ks] = *(const bf16x8*)(p + ks * 512);
        }
        #pragma unroll
        for (int h = 0; h < 2; ++h) {
            float4 f4[4];
            #pragma unroll
            for (int mm = 0; mm < 4; ++mm)
                f4[mm] = *(const float4*)&f_lds[s][(h * 4 + mm) * 16 + lk * 4];

            f32x4 g[4];
            #pragma unroll
            for (int mm = 0; mm < 4; ++mm) g[mm] = (f32x4){0.f, 0.f, 0.f, 0.f};

            #pragma unroll
            for (int ks = 0; ks < 4; ++ks)
                #pragma unroll
                for (int mm = 0; mm < 4; ++mm)
                    g[mm] = __builtin_amdgcn_mfma_f32_16x16x32_bf16(
                        a_pk[h * 4 + mm][ks], B[cur][ks], g[mm], 0, 0, 0);

            #pragma unroll
            for (int mm = 0; mm < 4; ++mm) {
                acc[h * 4 + mm][0] += f4[mm].x * g[mm][0];
                acc[h * 4 + mm][1] += f4[mm].y * g[mm][1];
                acc[h * 4 + mm][2] += f4[mm].z * g[mm][2];
                acc[h * 4 + mm][3] += f4[mm].w * g[mm][3];
            }
        }
    }

    // epilogue: C/D col=lm, row=lk*4+r
    const int col = z0 + wv * 16 + lm;
    #pragma unroll
    for (int m = 0; m < 8; ++m)
        #pragma unroll
        for (int r = 0; r < 4; ++r) {
            const int row = t0 + m * 16 + lk * 4 + r;
            if (USE_WS)
                dst[(size_t)kp * 524288 + (size_t)row * 128 + col] = acc[m][r];
            else
                atomicAdd(&dst[(size_t)row * 128 + col], acc[m][r]);
        }
}

__global__ __launch_bounds__(256) void cooc_reduce(const float* __restrict__ ws,
                                                   float* __restrict__ out) {
    const size_t idx = ((size_t)blockIdx.x * 256 + threadIdx.x) * 4;
    float4 a = *(const float4*)(ws + idx);
    #pragma unroll
    for (int k = 1; k < 8; ++k) {
        float4 b = *(const float4*)(ws + (size_t)k * 524288 + idx);
        a.x += b.x; a.y += b.y; a.z += b.z; a.w += b.w;
    }
    *(float4*)(out + idx) = a;
}

extern "C" void kernel_launch(void* const* d_in, const int* in_sizes, int n_in,
                              void* d_out, int out_size, void* d_ws, size_t ws_size,
                              hipStream_t stream) {
    const float* fa = (const float*)d_in[0];   // (4096,256): [:,0:128]=f, [:,128:256]=a
    const float* Cc = (const float*)d_in[1];   // (128,128,128)
    float* out = (float*)d_out;                // (4096,128)

    const size_t PART = (size_t)8 * 524288;                  // fp32 partials: 16 MiB
    const size_t CTOF = PART * sizeof(float);                // 16 MiB
    const size_t CTSZ = (size_t)128 * 128 * 128 * 2;         // 4 MiB
    const size_t APOF = CTOF + CTSZ;                         // 20 MiB
    const size_t APSZ = (size_t)4096 * 128 * 2;              // 1 MiB
    const size_t NEED_FULL = APOF + APSZ;
    const size_t NEED_CT   = CTSZ + APSZ;

    if (ws_size >= NEED_FULL) {
        ushort* CT  = (ushort*)((char*)d_ws + CTOF);
        ushort* APK = (ushort*)((char*)d_ws + APOF);
        cooc_transpose<<<512, 256, 0, stream>>>(Cc, CT);
        cooc_apack<<<256, 256, 0, stream>>>(fa, APK);
        cooc_main<1><<<512, 256, 0, stream>>>(fa, CT, APK, (float*)d_ws);
        cooc_reduce<<<512, 256, 0, stream>>>((const float*)d_ws, out);
    } else if (ws_size >= NEED_CT) {
        ushort* CT  = (ushort*)d_ws;
        ushort* APK = (ushort*)((char*)d_ws + CTSZ);
        cooc_transpose<<<512, 256, 0, stream>>>(Cc, CT);
        cooc_apack<<<256, 256, 0, stream>>>(fa, APK);
        (void)hipMemsetAsync(out, 0, (size_t)out_size * sizeof(float), stream);
        cooc_main<0><<<512, 256, 0, stream>>>(fa, CT, APK, out);
    } else {
        (void)hipMemsetAsync(out, 0, (size_t)out_size * sizeof(float), stream);
        cooc_main<0><<<512, 256, 0, stream>>>(fa, (const ushort*)d_ws,
                                              (const ushort*)d_ws, out);
    }
}

// Round 10
// 86.218 us; speedup vs baseline: 1.2126x; 1.0327x over previous
//
#include <hip/hip_runtime.h>
#include <hip/hip_bf16.h>

// out[t,z] = sum_i f[t,i] * ( sum_j a[t,j] * C[i,j,z] )
// R10 = R9 (fragment-major contiguous loads) + occupancy/latency fixes:
//  - wave tile 64x16 (a_pk 64 regs, live ~150) + launch_bounds(256,3)
//    -> 170-reg cap, 3 waves/SIMD (was 2 at 250 regs) for latency cover
//  - B prefetch distance 2 with 2 buffers (reload B[cur] for s+2 after use)
// Block 256 thr = 4 waves (2 mg x 2 zg) = 128 rows x 32 z.
// Grid 1024 = 32 mt x 4 zp x 8 kp; kp=bid&7 -> XCD-affine CT chunk in L2.
// ws: [0,16MB) fp32 partials [kp][4096][128]; [16,20MB) CTf; [20,21MB) APK.
//  CTf[i][z>>4][j>>3][z&15][j&7] bf16 ; APK[t>>4][ks][lk][lm][8k] bf16 —
//  every hot wave-load is ONE contiguous 1 KB segment (base + lane*16).

typedef __attribute__((ext_vector_type(8))) short bf16x8;
typedef __attribute__((ext_vector_type(4))) float f32x4;

__device__ __forceinline__ unsigned pkbf16(float x, float y) {
    __hip_bfloat162 h = __float22bfloat162_rn(make_float2(x, y));
    unsigned u; __builtin_memcpy(&u, &h, sizeof(u));
    return u;
}

// ---------- C[i][j][z] fp32 -> CTf fragment-major bf16 (verbatim R9) ----------
__global__ __launch_bounds__(256) void cooc_transpose(
    const float* __restrict__ Cc, ushort* __restrict__ CT)
{
    __shared__ float tile[32][132];
    const int i  = blockIdx.x >> 2;
    const int j0 = (blockIdx.x & 3) * 32;
    const int t  = threadIdx.x;
    {
        const int jj = t >> 3;
        const int zb = (t & 7) * 16;
        const float* src = Cc + (size_t)i * 16384 + (size_t)(j0 + jj) * 128 + zb;
        #pragma unroll
        for (int k = 0; k < 4; ++k)
            *(float4*)&tile[jj][zb + k * 4] = *(const float4*)(src + k * 4);
    }
    __syncthreads();
    {
        const int z = t >> 1;
        const int h = t & 1;
        unsigned o[8];
        #pragma unroll
        for (int p = 0; p < 8; ++p)
            o[p] = pkbf16(tile[h * 16 + 2 * p][z], tile[h * 16 + 2 * p + 1][z]);
        const int c0 = (j0 >> 3) + h * 2;
        ushort* dst = CT + (size_t)i * 16384 + (size_t)(z >> 4) * 2048
                         + (size_t)c0 * 128 + (z & 15) * 8;
        *(uint4*)dst         = make_uint4(o[0], o[1], o[2], o[3]);
        *(uint4*)(dst + 128) = make_uint4(o[4], o[5], o[6], o[7]);
    }
}

// ---------- a (fa[:,128:256]) -> APK fragment-major bf16 (verbatim R9) ----------
__global__ __launch_bounds__(256) void cooc_apack(
    const float* __restrict__ fa, ushort* __restrict__ APK)
{
    const int g = blockIdx.x;
    const int t = threadIdx.x;
    const int ks = t >> 6, lk = (t >> 4) & 3, lm = t & 15;
    const float* src = fa + (size_t)(g * 16 + lm) * 256 + 128 + ks * 32 + lk * 8;
    float4 q0 = *(const float4*)src;
    float4 q1 = *(const float4*)(src + 4);
    unsigned o0 = pkbf16(q0.x, q0.y), o1 = pkbf16(q0.z, q0.w);
    unsigned o2 = pkbf16(q1.x, q1.y), o3 = pkbf16(q1.z, q1.w);
    *(uint4*)(APK + (size_t)g * 2048 + t * 8) = make_uint4(o0, o1, o2, o3);
}

// ---------- main ----------
template<int USE_WS>
__global__ __launch_bounds__(256, 3) void cooc_main(
    const float* __restrict__ fa, const ushort* __restrict__ CT,
    const ushort* __restrict__ APK, float* __restrict__ dst)
{
    __shared__ float f_lds[16][128];       // 8 KB: f[i_local][row]

    const int bid = blockIdx.x;
    const int kp = bid & 7, zp = (bid >> 3) & 3, mtile = bid >> 5;
    const int t0 = mtile * 128, i0 = kp * 16;
    const int tid = threadIdx.x, lane = tid & 63, wv = tid >> 6;
    const int mg = wv >> 1, zg = wv & 1;   // 64-row group, 16-z group
    const int lm = lane & 15, lk = lane >> 4;

    // stage f -> LDS (transposed [i][row])
    {
        const int row = tid & 127;
        const int sh = (tid >> 7) * 8;
        const float* fp = fa + (size_t)(t0 + row) * 256 + i0 + sh;
        float4 v0 = *(const float4*)fp;
        float4 v1 = *(const float4*)(fp + 4);
        f_lds[sh + 0][row] = v0.x; f_lds[sh + 1][row] = v0.y;
        f_lds[sh + 2][row] = v0.z; f_lds[sh + 3][row] = v0.w;
        f_lds[sh + 4][row] = v1.x; f_lds[sh + 5][row] = v1.y;
        f_lds[sh + 6][row] = v1.z; f_lds[sh + 7][row] = v1.w;
    }

    // A fragments: 16 contiguous 1 KB wave-loads (rows mg*64 .. +63)
    bf16x8 a_pk[4][4];                     // 64 regs
    {
        const ushort* ap = APK + (size_t)((t0 >> 4) + mg * 4) * 2048 + lane * 8;
        #pragma unroll
        for (int m = 0; m < 4; ++m)
            #pragma unroll
            for (int ks = 0; ks < 4; ++ks)
                a_pk[m][ks] = *(const bf16x8*)(ap + (size_t)m * 2048 + ks * 512);
    }
    __syncthreads();   // f_lds ready; only barrier

    // B source (contiguous): CTf + i*16384 + (zp*2+zg)*2048 + lane*8
    const ushort* bsrc = CT + (size_t)i0 * 16384
                            + (size_t)(zp * 2 + zg) * 2048 + lane * 8;

    // prime prefetch: s=0 -> B[0], s=1 -> B[1]  (depth 2)
    bf16x8 B[2][4];
    #pragma unroll
    for (int ks = 0; ks < 4; ++ks) {
        B[0][ks] = *(const bf16x8*)(bsrc + ks * 512);
        B[1][ks] = *(const bf16x8*)(bsrc + 16384 + ks * 512);
    }

    float acc[4][4];
    #pragma unroll
    for (int m = 0; m < 4; ++m)
        #pragma unroll
        for (int r = 0; r < 4; ++r) acc[m][r] = 0.f;

    #pragma unroll 2
    for (int s = 0; s < 16; ++s) {
        const int cur = s & 1;

        // 4 independent MFMA chains, ks-outer (dep distance 4)
        f32x4 g[4];
        #pragma unroll
        for (int m = 0; m < 4; ++m) g[m] = (f32x4){0.f, 0.f, 0.f, 0.f};
        #pragma unroll
        for (int ks = 0; ks < 4; ++ks)
            #pragma unroll
            for (int m = 0; m < 4; ++m)
                g[m] = __builtin_amdgcn_mfma_f32_16x16x32_bf16(
                    a_pk[m][ks], B[cur][ks], g[m], 0, 0, 0);

        // reload B[cur] with slab s+2 (issues after MFMAs consume it; ~2-slab cover)
        if (s < 14) {
            const ushort* p = bsrc + (size_t)(s + 2) * 16384;
            #pragma unroll
            for (int ks = 0; ks < 4; ++ks)
                B[cur][ks] = *(const bf16x8*)(p + ks * 512);
        }

        // f read + fold (f latency covered by the MFMA chain completion)
        float4 f4[4];
        #pragma unroll
        for (int m = 0; m < 4; ++m)
            f4[m] = *(const float4*)&f_lds[s][mg * 64 + m * 16 + lk * 4];
        #pragma unroll
        for (int m = 0; m < 4; ++m) {
            acc[m][0] += f4[m].x * g[m][0];
            acc[m][1] += f4[m].y * g[m][1];
            acc[m][2] += f4[m].z * g[m][2];
            acc[m][3] += f4[m].w * g[m][3];
        }
    }

    // epilogue: C/D col=lm, row=lk*4+r
    const int col = zp * 32 + zg * 16 + lm;
    #pragma unroll
    for (int m = 0; m < 4; ++m)
        #pragma unroll
        for (int r = 0; r < 4; ++r) {
            const int row = t0 + mg * 64 + m * 16 + lk * 4 + r;
            if (USE_WS)
                dst[(size_t)kp * 524288 + (size_t)row * 128 + col] = acc[m][r];
            else
                atomicAdd(&dst[(size_t)row * 128 + col], acc[m][r]);
        }
}

__global__ __launch_bounds__(256) void cooc_reduce(const float* __restrict__ ws,
                                                   float* __restrict__ out) {
    const size_t idx = ((size_t)blockIdx.x * 256 + threadIdx.x) * 4;
    float4 a = *(const float4*)(ws + idx);
    #pragma unroll
    for (int k = 1; k < 8; ++k) {
        float4 b = *(const float4*)(ws + (size_t)k * 524288 + idx);
        a.x += b.x; a.y += b.y; a.z += b.z; a.w += b.w;
    }
    *(float4*)(out + idx) = a;
}

extern "C" void kernel_launch(void* const* d_in, const int* in_sizes, int n_in,
                              void* d_out, int out_size, void* d_ws, size_t ws_size,
                              hipStream_t stream) {
    const float* fa = (const float*)d_in[0];   // (4096,256): [:,0:128]=f, [:,128:256]=a
    const float* Cc = (const float*)d_in[1];   // (128,128,128)
    float* out = (float*)d_out;                // (4096,128)

    const size_t PART = (size_t)8 * 524288;                  // fp32 partials: 16 MiB
    const size_t CTOF = PART * sizeof(float);                // 16 MiB
    const size_t CTSZ = (size_t)128 * 128 * 128 * 2;         // 4 MiB
    const size_t APOF = CTOF + CTSZ;                         // 20 MiB
    const size_t APSZ = (size_t)4096 * 128 * 2;              // 1 MiB
    const size_t NEED_FULL = APOF + APSZ;
    const size_t NEED_CT   = CTSZ + APSZ;

    if (ws_size >= NEED_FULL) {
        ushort* CT  = (ushort*)((char*)d_ws + CTOF);
        ushort* APK = (ushort*)((char*)d_ws + APOF);
        cooc_transpose<<<512, 256, 0, stream>>>(Cc, CT);
        cooc_apack<<<256, 256, 0, stream>>>(fa, APK);
        cooc_main<1><<<1024, 256, 0, stream>>>(fa, CT, APK, (float*)d_ws);
        cooc_reduce<<<512, 256, 0, stream>>>((const float*)d_ws, out);
    } else if (ws_size >= NEED_CT) {
        ushort* CT  = (ushort*)d_ws;
        ushort* APK = (ushort*)((char*)d_ws + CTSZ);
        cooc_transpose<<<512, 256, 0, stream>>>(Cc, CT);
        cooc_apack<<<256, 256, 0, stream>>>(fa, APK);
        (void)hipMemsetAsync(out, 0, (size_t)out_size * sizeof(float), stream);
        cooc_main<0><<<1024, 256, 0, stream>>>(fa, CT, APK, out);
    } else {
        (void)hipMemsetAsync(out, 0, (size_t)out_size * sizeof(float), stream);
        cooc_main<0><<<1024, 256, 0, stream>>>(fa, (const ushort*)d_ws,
                                               (const ushort*)d_ws, out);
    }
}

// Round 11
// 86.176 us; speedup vs baseline: 1.2132x; 1.0005x over previous
//
#include <hip/hip_runtime.h>
#include <hip/hip_bf16.h>

// out[t,z] = sum_i f[t,i] * ( sum_j a[t,j] * C[i,j,z] )
// R11 = R10 + intra-block LDS B-sharing (halves L2 traffic: mg-wave pairs no
// longer duplicate loads) + merged prep kernel + f as bf16 in LDS.
// Per slab: each wave global-loads 2/4 ks-chunks (1 KB contiguous each),
// ds_writes them; all 4 waves ds_read the full 4-chunk slab. Double-buffered
// LDS + per-slab __syncthreads (drain covered by depth-2 pipeline + 3 blk/CU).
// Wave tile 64x16, block 4 waves (2mg x 2zg), grid 1024 = 32mt x 4zp x 8kp,
// kp=bid&7 -> XCD-affine CT chunk. launch_bounds(256,3) -> 3 waves/SIMD.
// ws: [0,16MB) fp32 partials [kp][4096][128]; [16,20MB) CTf; [20,21MB) APK.

typedef __attribute__((ext_vector_type(8))) short bf16x8;
typedef __attribute__((ext_vector_type(4))) float f32x4;

__device__ __forceinline__ unsigned pkbf16(float x, float y) {
    __hip_bfloat162 h = __float22bfloat162_rn(make_float2(x, y));
    unsigned u; __builtin_memcpy(&u, &h, sizeof(u));
    return u;
}
__device__ __forceinline__ float bf16lo(unsigned u) {
    unsigned v = u << 16; float f; __builtin_memcpy(&f, &v, 4); return f;
}
__device__ __forceinline__ float bf16hi(unsigned u) {
    unsigned v = u & 0xFFFF0000u; float f; __builtin_memcpy(&f, &v, 4); return f;
}

// ---------- prep: transpose C->CTf (bid<512) + pack a->APK (bid>=512) ----------
__global__ __launch_bounds__(256) void cooc_prep(
    const float* __restrict__ Cc, const float* __restrict__ fa,
    ushort* __restrict__ CT, ushort* __restrict__ APK)
{
    const int bid = blockIdx.x;
    const int t = threadIdx.x;
    if (bid < 512) {
        __shared__ float tile[32][132];
        const int i  = bid >> 2;
        const int j0 = (bid & 3) * 32;
        {
            const int jj = t >> 3;
            const int zb = (t & 7) * 16;
            const float* src = Cc + (size_t)i * 16384 + (size_t)(j0 + jj) * 128 + zb;
            #pragma unroll
            for (int k = 0; k < 4; ++k)
                *(float4*)&tile[jj][zb + k * 4] = *(const float4*)(src + k * 4);
        }
        __syncthreads();
        {
            const int z = t >> 1;
            const int h = t & 1;
            unsigned o[8];
            #pragma unroll
            for (int p = 0; p < 8; ++p)
                o[p] = pkbf16(tile[h * 16 + 2 * p][z], tile[h * 16 + 2 * p + 1][z]);
            const int c0 = (j0 >> 3) + h * 2;
            ushort* dst = CT + (size_t)i * 16384 + (size_t)(z >> 4) * 2048
                             + (size_t)c0 * 128 + (z & 15) * 8;
            *(uint4*)dst         = make_uint4(o[0], o[1], o[2], o[3]);
            *(uint4*)(dst + 128) = make_uint4(o[4], o[5], o[6], o[7]);
        }
    } else {
        const int g = bid - 512;           // 0..255: 16-row group
        const int ks = t >> 6, lk = (t >> 4) & 3, lm = t & 15;
        const float* src = fa + (size_t)(g * 16 + lm) * 256 + 128 + ks * 32 + lk * 8;
        float4 q0 = *(const float4*)src;
        float4 q1 = *(const float4*)(src + 4);
        *(uint4*)(APK + (size_t)g * 2048 + t * 8) =
            make_uint4(pkbf16(q0.x, q0.y), pkbf16(q0.z, q0.w),
                       pkbf16(q1.x, q1.y), pkbf16(q1.z, q1.w));
    }
}

// ---------- main ----------
template<int USE_WS>
__global__ __launch_bounds__(256, 3) void cooc_main(
    const float* __restrict__ fa, const ushort* __restrict__ CT,
    const ushort* __restrict__ APK, float* __restrict__ dst)
{
    __shared__ ushort Bbuf[2][2][4][512];   // [parity][zg][ks][lane*8] : 16 KB
    __shared__ ushort fpk[16][128];         // f bf16 [i_local][row]     : 4 KB

    const int bid = blockIdx.x;
    const int kp = bid & 7, zp = (bid >> 3) & 3, mtile = bid >> 5;
    const int t0 = mtile * 128, i0 = kp * 16;
    const int tid = threadIdx.x, lane = tid & 63, wv = tid >> 6;
    const int mg = wv >> 1, zg = wv & 1;
    const int lm = lane & 15, lk = lane >> 4;

    // stage f -> LDS as bf16 [i][row]
    {
        const int row = tid & 127;
        const int sh = (tid >> 7) * 8;
        const float* fp = fa + (size_t)(t0 + row) * 256 + i0 + sh;
        float4 v0 = *(const float4*)fp;
        float4 v1 = *(const float4*)(fp + 4);
        fpk[sh + 0][row] = (ushort)(pkbf16(v0.x, v0.x) & 0xFFFF);
        fpk[sh + 1][row] = (ushort)(pkbf16(v0.y, v0.y) & 0xFFFF);
        fpk[sh + 2][row] = (ushort)(pkbf16(v0.z, v0.z) & 0xFFFF);
        fpk[sh + 3][row] = (ushort)(pkbf16(v0.w, v0.w) & 0xFFFF);
        fpk[sh + 4][row] = (ushort)(pkbf16(v1.x, v1.x) & 0xFFFF);
        fpk[sh + 5][row] = (ushort)(pkbf16(v1.y, v1.y) & 0xFFFF);
        fpk[sh + 6][row] = (ushort)(pkbf16(v1.z, v1.z) & 0xFFFF);
        fpk[sh + 7][row] = (ushort)(pkbf16(v1.w, v1.w) & 0xFFFF);
    }

    // A fragments: 16 contiguous 1 KB wave-loads (rows mg*64 .. +63)
    bf16x8 a_pk[4][4];                     // 64 regs
    {
        const ushort* ap = APK + (size_t)((t0 >> 4) + mg * 4) * 2048 + lane * 8;
        #pragma unroll
        for (int m = 0; m < 4; ++m)
            #pragma unroll
            for (int ks = 0; ks < 4; ++ks)
                a_pk[m][ks] = *(const bf16x8*)(ap + (size_t)m * 2048 + ks * 512);
    }

    // B chunk source: this wave loads ks = 2*mg, 2*mg+1 for its zg
    const ushort* bchunk = CT + (size_t)i0 * 16384
                              + (size_t)(zp * 2 + zg) * 2048
                              + (size_t)(2 * mg) * 512 + lane * 8;

    bf16x8 Bg[2][2];                       // [parity][chunk] : 16 regs
    #pragma unroll
    for (int c = 0; c < 2; ++c) {
        Bg[0][c] = *(const bf16x8*)(bchunk + c * 512);              // B(0)
        Bg[1][c] = *(const bf16x8*)(bchunk + 16384 + c * 512);      // B(1)
    }
    // publish B(0); B(1) published during slab 0
    #pragma unroll
    for (int c = 0; c < 2; ++c)
        *(bf16x8*)&Bbuf[0][zg][2 * mg + c][lane * 8] = Bg[0][c];
    __syncthreads();

    float acc[4][4];
    #pragma unroll
    for (int m = 0; m < 4; ++m)
        #pragma unroll
        for (int r = 0; r < 4; ++r) acc[m][r] = 0.f;

    #pragma unroll 2
    for (int s = 0; s < 16; ++s) {
        const int cur = s & 1;

        // 1) publish B(s+1) to the other LDS buffer (loaded at s-1)
        if (s < 15)
            #pragma unroll
            for (int c = 0; c < 2; ++c)
                *(bf16x8*)&Bbuf[cur ^ 1][zg][2 * mg + c][lane * 8] = Bg[cur ^ 1][c];

        // 2) issue global load of B(s+2) into freed parity regs
        if (s < 14) {
            const ushort* p = bchunk + (size_t)(s + 2) * 16384;
            #pragma unroll
            for (int c = 0; c < 2; ++c)
                Bg[cur][c] = *(const bf16x8*)(p + c * 512);
        }

        // 3) read full slab B(s) from LDS (4 x b128, conflict-free)
        bf16x8 Bl[4];
        #pragma unroll
        for (int ks = 0; ks < 4; ++ks)
            Bl[ks] = *(const bf16x8*)&Bbuf[cur][zg][ks][lane * 8];

        // 4) f for this slab: 4 x ds_read_b64 (bf16 x4: rows lk*4..+3)
        uint2 fq[4];
        #pragma unroll
        for (int m = 0; m < 4; ++m)
            fq[m] = *(const uint2*)&fpk[s][mg * 64 + m * 16 + lk * 4];

        // 5) ks-outer / m-inner: 4 independent MFMA chains
        f32x4 g[4];
        #pragma unroll
        for (int m = 0; m < 4; ++m) g[m] = (f32x4){0.f, 0.f, 0.f, 0.f};
        #pragma unroll
        for (int ks = 0; ks < 4; ++ks)
            #pragma unroll
            for (int m = 0; m < 4; ++m)
                g[m] = __builtin_amdgcn_mfma_f32_16x16x32_bf16(
                    a_pk[m][ks], Bl[ks], g[m], 0, 0, 0);

        // 6) fold with f (bf16 -> f32 unpack + FMA)
        #pragma unroll
        for (int m = 0; m < 4; ++m) {
            acc[m][0] += bf16lo(fq[m].x) * g[m][0];
            acc[m][1] += bf16hi(fq[m].x) * g[m][1];
            acc[m][2] += bf16lo(fq[m].y) * g[m][2];
            acc[m][3] += bf16hi(fq[m].y) * g[m][3];
        }

        __syncthreads();   // publishes step-1 writes for slab s+1
    }

    // epilogue: C/D col=lm, row=lk*4+r
    const int col = zp * 32 + zg * 16 + lm;
    #pragma unroll
    for (int m = 0; m < 4; ++m)
        #pragma unroll
        for (int r = 0; r < 4; ++r) {
            const int row = t0 + mg * 64 + m * 16 + lk * 4 + r;
            if (USE_WS)
                dst[(size_t)kp * 524288 + (size_t)row * 128 + col] = acc[m][r];
            else
                atomicAdd(&dst[(size_t)row * 128 + col], acc[m][r]);
        }
}

__global__ __launch_bounds__(256) void cooc_reduce(const float* __restrict__ ws,
                                                   float* __restrict__ out) {
    const size_t idx = ((size_t)blockIdx.x * 256 + threadIdx.x) * 4;
    float4 a = *(const float4*)(ws + idx);
    #pragma unroll
    for (int k = 1; k < 8; ++k) {
        float4 b = *(const float4*)(ws + (size_t)k * 524288 + idx);
        a.x += b.x; a.y += b.y; a.z += b.z; a.w += b.w;
    }
    *(float4*)(out + idx) = a;
}

extern "C" void kernel_launch(void* const* d_in, const int* in_sizes, int n_in,
                              void* d_out, int out_size, void* d_ws, size_t ws_size,
                              hipStream_t stream) {
    const float* fa = (const float*)d_in[0];   // (4096,256): [:,0:128]=f, [:,128:256]=a
    const float* Cc = (const float*)d_in[1];   // (128,128,128)
    float* out = (float*)d_out;                // (4096,128)

    const size_t PART = (size_t)8 * 524288;                  // fp32 partials: 16 MiB
    const size_t CTOF = PART * sizeof(float);                // 16 MiB
    const size_t CTSZ = (size_t)128 * 128 * 128 * 2;         // 4 MiB
    const size_t APOF = CTOF + CTSZ;                         // 20 MiB
    const size_t APSZ = (size_t)4096 * 128 * 2;              // 1 MiB
    const size_t NEED_FULL = APOF + APSZ;
    const size_t NEED_CT   = CTSZ + APSZ;

    if (ws_size >= NEED_FULL) {
        ushort* CT  = (ushort*)((char*)d_ws + CTOF);
        ushort* APK = (ushort*)((char*)d_ws + APOF);
        cooc_prep<<<768, 256, 0, stream>>>(Cc, fa, CT, APK);
        cooc_main<1><<<1024, 256, 0, stream>>>(fa, CT, APK, (float*)d_ws);
        cooc_reduce<<<512, 256, 0, stream>>>((const float*)d_ws, out);
    } else if (ws_size >= NEED_CT) {
        ushort* CT  = (ushort*)d_ws;
        ushort* APK = (ushort*)((char*)d_ws + CTSZ);
        cooc_prep<<<768, 256, 0, stream>>>(Cc, fa, CT, APK);
        (void)hipMemsetAsync(out, 0, (size_t)out_size * sizeof(float), stream);
        cooc_main<0><<<1024, 256, 0, stream>>>(fa, CT, APK, out);
    } else {
        (void)hipMemsetAsync(out, 0, (size_t)out_size * sizeof(float), stream);
        cooc_main<0><<<1024, 256, 0, stream>>>(fa, (const ushort*)d_ws,
                                               (const ushort*)d_ws, out);
    }
}